// Round 7
// baseline (214.361 us; speedup 1.0000x reference)
//
#include <hip/hip_runtime.h>

#define SEQ  4096
#define DMODEL 1024
#define QTOT 16384           // B*S
#define QSCALE 0.18033688011112042f   // (1/sqrt(64)) * log2(e), folded into Q

typedef __bf16 bf16x8 __attribute__((ext_vector_type(8)));
typedef __fp16 h16x4 __attribute__((ext_vector_type(4)));
typedef __fp16 h16x2 __attribute__((ext_vector_type(2)));
typedef unsigned short u16x8 __attribute__((ext_vector_type(8)));
typedef float f32x4 __attribute__((ext_vector_type(4)));

// ---------- helpers ----------
static __device__ __forceinline__ unsigned short f2bfbits(float f) {
    unsigned int u = __builtin_bit_cast(unsigned int, f);
    unsigned int lsb = (u >> 16) & 1u;
    u += 0x7fffu + lsb;                      // round-to-nearest-even
    return (unsigned short)(u >> 16);
}

static __device__ __forceinline__ bf16x8 ld_frag(const unsigned short* p) {
    uint4 u = *reinterpret_cast<const uint4*>(p);
    return __builtin_bit_cast(bf16x8, u);
}

static __device__ __forceinline__ h16x4 ld_h16x4(const __fp16* p) {
    return *reinterpret_cast<const h16x4*>(p);   // 8-byte load
}

// ---------- kernel 1: weights -> bf16, pre-swizzled into MFMA B-fragment order ----------
// WtS: frag(kc,nt) at ushort offset (kc*12+nt)*512; lane l owns [l*8, l*8+8)
// element j of lane l = W^T[nt*16 + (l&15)][kc*32 + (l>>4)*8 + j]
__global__ void prep_weights(const float* __restrict__ Wq,
                             const float* __restrict__ Wk,
                             const float* __restrict__ Wv,
                             unsigned short* __restrict__ WtS) {
    int o = blockIdx.x * 256 + threadIdx.x;      // 192*1024 total
    int f = o >> 9, q = o & 511;
    int lane = q >> 3, j = q & 7;
    int kc = f / 12, nt = f - kc * 12;
    int n = nt * 16 + (lane & 15);
    int k = kc * 32 + (lane >> 4) * 8 + j;
    float v;
    if (n < 64)       v = Wq[k * 64 + n];
    else if (n < 128) v = Wk[k * 64 + (n - 64)];
    else              v = Wv[k * 64 + (n - 128)];
    WtS[o] = f2bfbits(v);
}

// ---------- kernel 2: QKV projection, K-split ACROSS WAVES, LDS merge ----------
// grid 1024 x 256 thr. Block = 16 tokens; wave w covers k in [w*256, w*256+256).
// No barriers in main loop; emb read directly in A-frag layout (128B segments/row).
__global__ __launch_bounds__(256, 4) void proj(
        const float* __restrict__ emb, const unsigned short* __restrict__ WtS,
        const float* __restrict__ bq, const float* __restrict__ bk,
        const float* __restrict__ bv,
        unsigned short* __restrict__ Qb, unsigned short* __restrict__ Kb,
        __fp16* __restrict__ VTH) {
    __shared__ __align__(16) float red[2][64 * 52];   // 2 slots, lane stride 52

    const int tid = threadIdx.x;
    const int w = tid >> 6, lane = tid & 63;
    const int c = lane & 15, qd = lane >> 4;
    const int tb = blockIdx.x;                   // token block (16 tokens)

    const float* ap = emb + (size_t)(tb * 16 + c) * DMODEL + w * 256 + qd * 8;
    const unsigned short* wp = WtS + (size_t)(w * 8) * 6144 + lane * 8;

    f32x4 acc[12];
#pragma unroll
    for (int i = 0; i < 12; i++) acc[i] = (f32x4){0.f, 0.f, 0.f, 0.f};

    float4 e0a = *reinterpret_cast<const float4*>(ap);
    float4 e0b = *reinterpret_cast<const float4*>(ap + 4);
    float4 e1a = *reinterpret_cast<const float4*>(ap + 32);
    float4 e1b = *reinterpret_cast<const float4*>(ap + 36);

#pragma unroll
    for (int s = 0; s < 8; s++) {
        float4 e2a, e2b;
        if (s < 6) {
            e2a = *reinterpret_cast<const float4*>(ap + (s + 2) * 32);
            e2b = *reinterpret_cast<const float4*>(ap + (s + 2) * 32 + 4);
        } else { e2a = e1a; e2b = e1b; }

        u16x8 at;
        at[0] = f2bfbits(e0a.x); at[1] = f2bfbits(e0a.y);
        at[2] = f2bfbits(e0a.z); at[3] = f2bfbits(e0a.w);
        at[4] = f2bfbits(e0b.x); at[5] = f2bfbits(e0b.y);
        at[6] = f2bfbits(e0b.z); at[7] = f2bfbits(e0b.w);
        bf16x8 af = __builtin_bit_cast(bf16x8, at);

#pragma unroll
        for (int nt = 0; nt < 12; nt++) {
            bf16x8 wf = ld_frag(wp + (size_t)(s * 12 + nt) * 512);
            acc[nt] = __builtin_amdgcn_mfma_f32_16x16x32_bf16(af, wf, acc[nt], 0, 0, 0);
        }
        e0a = e1a; e0b = e1b; e1a = e2a; e1b = e2b;
    }

    // LDS tree-merge of the 4 k-partials
    if (w >= 2) {
        float* rp = &red[w - 2][lane * 52];
#pragma unroll
        for (int i = 0; i < 12; i++) *reinterpret_cast<f32x4*>(rp + i * 4) = acc[i];
    }
    __syncthreads();
    if (w < 2) {
        float* rp = &red[w][lane * 52];
#pragma unroll
        for (int i = 0; i < 12; i++) acc[i] += *reinterpret_cast<const f32x4*>(rp + i * 4);
    }
    __syncthreads();
    if (w == 1) {
        float* rp = &red[0][lane * 52];
#pragma unroll
        for (int i = 0; i < 12; i++) *reinterpret_cast<f32x4*>(rp + i * 4) = acc[i];
    }
    __syncthreads();
    if (w == 0) {
        float* rp = &red[0][lane * 52];
#pragma unroll
        for (int i = 0; i < 12; i++) acc[i] += *reinterpret_cast<const f32x4*>(rp + i * 4);

#pragma unroll
        for (int nt = 0; nt < 12; nt++) {
            int n = nt * 16 + c;
            float bias = (n < 64) ? bq[n] : (n < 128) ? bk[n - 64] : bv[n - 128];
#pragma unroll
            for (int r = 0; r < 4; r++) {
                int token = tb * 16 + qd * 4 + r;
                float v = acc[nt][r] + bias;
                if (n < 64)
                    Qb[(size_t)token * 64 + n] = f2bfbits(v * QSCALE);
                else if (n < 128)
                    Kb[(size_t)token * 64 + (n - 64)] = f2bfbits(v);
                else {
                    int bb = token >> 12, ss = token & 4095;
                    VTH[((size_t)bb * 64 + (n - 128)) * SEQ + ss] = (__fp16)v;
                }
            }
        }
    }
}

// ---------- kernel 3: transposed-score flash attention, zero P-movement ----------
// Scores computed as S^T (A=K, B=Q); exp2+pkrtz output IS the 16x16x16 B-fragment
// for PV (A=V^T fp16). grid 512 (4b x 128 qblk, XCD-pinned); 512 thr = 8 waves;
// wave w owns t-slice [w*512, w*512+512) in 32 steps of 16 t; end LDS tree-reduce.
__global__ __launch_bounds__(512, 4) void attn(
        const unsigned short* __restrict__ Qb, const unsigned short* __restrict__ Kb,
        const __fp16* __restrict__ VTH, float* __restrict__ out) {
    __shared__ __align__(16) float red[4][64 * 36];   // 36,864 B
    __shared__ float l_all[8][32];

    const int tid = threadIdx.x;
    const int w = tid >> 6, lane = tid & 63;
    const int c = lane & 15, qd = lane >> 4;
    const int g3 = blockIdx.x & 7;               // XCD pin: b*2 + (qblk&1)
    const int b = g3 >> 1;
    const int qblk = ((blockIdx.x >> 3) << 1) | (g3 & 1);
    const int qbase = qblk * 32;
    const int tstart = w * 512;

    // Q B-fragments (bf16, pre-scaled by QSCALE)
    bf16x8 q0[2], q1[2];
#pragma unroll
    for (int qs = 0; qs < 2; qs++) {
        const unsigned short* Qp = Qb + ((size_t)(b << 12) + qbase + qs * 16 + c) * 64 + qd * 8;
        q0[qs] = ld_frag(Qp);
        q1[qs] = ld_frag(Qp + 32);
    }

    const unsigned short* Kbase = Kb + (size_t)(b << 12) * 64;
    const __fp16* Vbase = VTH + ((size_t)b * 64 << 12);

    f32x4 acc[8];                                // [qs][nt], O^T layout
#pragma unroll
    for (int i = 0; i < 8; i++) acc[i] = (f32x4){0.f, 0.f, 0.f, 0.f};
    float lsum[2] = {0.f, 0.f};

    // prefetch step 0
    bf16x8 ka = ld_frag(Kbase + (size_t)(tstart + c) * 64 + qd * 8);
    bf16x8 kb2 = ld_frag(Kbase + (size_t)(tstart + c) * 64 + 32 + qd * 8);
    h16x4 vf[4];
#pragma unroll
    for (int nt = 0; nt < 4; nt++)
        vf[nt] = ld_h16x4(Vbase + ((size_t)(nt * 16 + c) << 12) + tstart + qd * 4);

    for (int s = 0; s < 32; s++) {
        const int t0 = tstart + s * 16;
        bf16x8 nka, nkb;
        h16x4 nv[4];
        if (s < 31) {
            nka = ld_frag(Kbase + (size_t)(t0 + 16 + c) * 64 + qd * 8);
            nkb = ld_frag(Kbase + (size_t)(t0 + 16 + c) * 64 + 32 + qd * 8);
#pragma unroll
            for (int nt = 0; nt < 4; nt++)
                nv[nt] = ld_h16x4(Vbase + ((size_t)(nt * 16 + c) << 12) + t0 + 16 + qd * 4);
        } else { nka = ka; nkb = kb2; nv[0] = vf[0]; nv[1] = vf[1]; nv[2] = vf[2]; nv[3] = vf[3]; }

        // S^T tile per qs: lane holds t = t0 + qd*4 + r, q = qs*16 + c
        h16x4 pf[2];
#pragma unroll
        for (int qs = 0; qs < 2; qs++) {
            f32x4 z = (f32x4){0.f, 0.f, 0.f, 0.f};
            z = __builtin_amdgcn_mfma_f32_16x16x32_bf16(ka, q0[qs], z, 0, 0, 0);
            z = __builtin_amdgcn_mfma_f32_16x16x32_bf16(kb2, q1[qs], z, 0, 0, 0);
            float p0 = __builtin_amdgcn_exp2f(z[0]);
            float p1 = __builtin_amdgcn_exp2f(z[1]);
            float p2 = __builtin_amdgcn_exp2f(z[2]);
            float p3 = __builtin_amdgcn_exp2f(z[3]);
            lsum[qs] += (p0 + p1) + (p2 + p3);
            unsigned int lo = __builtin_bit_cast(unsigned int,
                                __builtin_amdgcn_cvt_pkrtz(p0, p1));
            unsigned int hi = __builtin_bit_cast(unsigned int,
                                __builtin_amdgcn_cvt_pkrtz(p2, p3));
            unsigned long long uu = ((unsigned long long)hi << 32) | lo;
            pf[qs] = __builtin_bit_cast(h16x4, uu);
        }

        // PV: acc[qs][nt] += V^T-frag(A) x P^T-frag(B), K=16 fp16 MFMA
#pragma unroll
        for (int nt = 0; nt < 4; nt++)
#pragma unroll
            for (int qs = 0; qs < 2; qs++)
                acc[qs * 4 + nt] = __builtin_amdgcn_mfma_f32_16x16x16f16(
                    vf[nt], pf[qs], acc[qs * 4 + nt], 0, 0, 0);

        ka = nka; kb2 = nkb;
        vf[0] = nv[0]; vf[1] = nv[1]; vf[2] = nv[2]; vf[3] = nv[3];
    }

    // l: reduce across qd (lanes with same c), store per-wave partial
#pragma unroll
    for (int qs = 0; qs < 2; qs++) {
        lsum[qs] += __shfl_xor(lsum[qs], 16);
        lsum[qs] += __shfl_xor(lsum[qs], 32);
    }
    if (qd == 0) {
        l_all[w][c] = lsum[0];
        l_all[w][16 + c] = lsum[1];
    }

    // tree-reduce acc over 8 waves
    __syncthreads();
    if (w >= 4) {
        float* rp = &red[w - 4][lane * 36];
#pragma unroll
        for (int i = 0; i < 8; i++) *reinterpret_cast<f32x4*>(rp + i * 4) = acc[i];
    }
    __syncthreads();
    if (w < 4) {
        float* rp = &red[w][lane * 36];
#pragma unroll
        for (int i = 0; i < 8; i++) acc[i] += *reinterpret_cast<const f32x4*>(rp + i * 4);
    }
    __syncthreads();
    if (w == 2 || w == 3) {
        float* rp = &red[w - 2][lane * 36];
#pragma unroll
        for (int i = 0; i < 8; i++) *reinterpret_cast<f32x4*>(rp + i * 4) = acc[i];
    }
    __syncthreads();
    if (w < 2) {
        float* rp = &red[w][lane * 36];
#pragma unroll
        for (int i = 0; i < 8; i++) acc[i] += *reinterpret_cast<const f32x4*>(rp + i * 4);
    }
    __syncthreads();
    if (w == 1) {
        float* rp = &red[0][lane * 36];
#pragma unroll
        for (int i = 0; i < 8; i++) *reinterpret_cast<f32x4*>(rp + i * 4) = acc[i];
    }
    __syncthreads();
    if (w == 0) {
        float* rp = &red[0][lane * 36];
#pragma unroll
        for (int i = 0; i < 8; i++) acc[i] += *reinterpret_cast<const f32x4*>(rp + i * 4);

#pragma unroll
        for (int qs = 0; qs < 2; qs++) {
            float l = 0.f;
#pragma unroll
            for (int ww = 0; ww < 8; ww++) l += l_all[ww][qs * 16 + c];
            float inv = 1.0f / l;
            size_t row = (size_t)(b << 12) + qbase + qs * 16 + c;
#pragma unroll
            for (int nt = 0; nt < 4; nt++) {
                f32x4 o = acc[qs * 4 + nt] * inv;
                *reinterpret_cast<f32x4*>(out + row * 64 + nt * 16 + qd * 4) = o;
            }
        }
    }
}

// ---------- launch ----------
extern "C" void kernel_launch(void* const* d_in, const int* in_sizes, int n_in,
                              void* d_out, int out_size, void* d_ws, size_t ws_size,
                              hipStream_t stream) {
    const float* emb = (const float*)d_in[0];
    const float* Wq  = (const float*)d_in[1];
    const float* bq  = (const float*)d_in[2];
    const float* Wk  = (const float*)d_in[3];
    const float* bk  = (const float*)d_in[4];
    const float* Wv  = (const float*)d_in[5];
    const float* bv  = (const float*)d_in[6];
    float* out = (float*)d_out;

    unsigned short* ws = (unsigned short*)d_ws;
    unsigned short* WtS = ws;                      // 192*1024 ushort
    unsigned short* Qb = ws + 192 * 1024;          // QTOT*64 bf16
    unsigned short* Kb = Qb + QTOT * 64;           // QTOT*64 bf16
    __fp16* VTH = (__fp16*)(Kb + QTOT * 64);       // [b][v][t] fp16

    prep_weights<<<768, 256, 0, stream>>>(Wq, Wk, Wv, WtS);
    proj<<<1024, 256, 0, stream>>>(emb, WtS, bq, bk, bv, Qb, Kb, VTH);
    attn<<<512, 512, 0, stream>>>(Qb, Kb, VTH, out);
}

// Round 8
// 193.996 us; speedup vs baseline: 1.1050x; 1.1050x over previous
//
#include <hip/hip_runtime.h>

#define SEQ  4096
#define DMODEL 1024
#define QTOT 16384           // B*S
#define QSCALE 0.18033688011112042f   // (1/sqrt(64)) * log2(e), folded into Q

typedef __bf16 bf16x8 __attribute__((ext_vector_type(8)));
typedef unsigned short u16x8 __attribute__((ext_vector_type(8)));
typedef float f32x4 __attribute__((ext_vector_type(4)));

// ---------- helpers ----------
static __device__ __forceinline__ unsigned short f2bfbits(float f) {
    unsigned int u = __builtin_bit_cast(unsigned int, f);
    unsigned int lsb = (u >> 16) & 1u;
    u += 0x7fffu + lsb;                      // round-to-nearest-even
    return (unsigned short)(u >> 16);
}

static __device__ __forceinline__ bf16x8 ld_frag(const unsigned short* p) {
    uint4 u = *reinterpret_cast<const uint4*>(p);
    return __builtin_bit_cast(bf16x8, u);
}

// ---------- kernel 1: weights -> bf16, pre-swizzled into MFMA B-fragment order ----------
// WtS: frag(kc,nt) at ushort offset (kc*12+nt)*512; lane l owns [l*8, l*8+8)
// element j of lane l = W^T[nt*16 + (l&15)][kc*32 + (l>>4)*8 + j]
__global__ void prep_weights(const float* __restrict__ Wq,
                             const float* __restrict__ Wk,
                             const float* __restrict__ Wv,
                             unsigned short* __restrict__ WtS) {
    int o = blockIdx.x * 256 + threadIdx.x;      // 192*1024 total
    int f = o >> 9, q = o & 511;
    int lane = q >> 3, j = q & 7;
    int kc = f / 12, nt = f - kc * 12;
    int n = nt * 16 + (lane & 15);
    int k = kc * 32 + (lane >> 4) * 8 + j;
    float v;
    if (n < 64)       v = Wq[k * 64 + n];
    else if (n < 128) v = Wk[k * 64 + (n - 64)];
    else              v = Wv[k * 64 + (n - 128)];
    WtS[o] = f2bfbits(v);
}

// ---------- kernel 2: QKV projection ----------
// grid 1024 x 512 thr. Block = 16 tokens. Wave (kq,nh): k-quarter kq (256 k),
// n-half nh (6 of 12 n-frags). W frags register-prefetched depth-1 from L2;
// emb depth-2; LDS tree-merge of 4 k-partials per n-half.
__global__ __launch_bounds__(512) void proj(
        const float* __restrict__ emb, const unsigned short* __restrict__ WtS,
        const float* __restrict__ bq, const float* __restrict__ bk,
        const float* __restrict__ bv,
        unsigned short* __restrict__ Qb, unsigned short* __restrict__ Kb,
        unsigned short* __restrict__ VT) {
    __shared__ __align__(16) float red[4][64 * 25];   // 25.6 KB, stride 25 (2-way banks)

    const int tid = threadIdx.x;
    const int w = tid >> 6, lane = tid & 63;
    const int c = lane & 15, qd = lane >> 4;
    const int kq = w >> 1, nh = w & 1;
    const int tb = blockIdx.x;

    const float* ap = emb + (size_t)(tb * 16 + c) * DMODEL + kq * 256 + qd * 8;
    const unsigned short* wp = WtS + (size_t)(kq * 8) * 6144 + (nh * 6) * 512 + lane * 8;

    f32x4 acc[6];
#pragma unroll
    for (int i = 0; i < 6; i++) acc[i] = (f32x4){0.f, 0.f, 0.f, 0.f};

    float4 e0a = *reinterpret_cast<const float4*>(ap);
    float4 e0b = *reinterpret_cast<const float4*>(ap + 4);
    float4 e1a = *reinterpret_cast<const float4*>(ap + 32);
    float4 e1b = *reinterpret_cast<const float4*>(ap + 36);
    bf16x8 wc[6], wn[6];
#pragma unroll
    for (int nt = 0; nt < 6; nt++) wc[nt] = ld_frag(wp + nt * 512);

#pragma unroll
    for (int s = 0; s < 8; s++) {
        if (s < 7) {
#pragma unroll
            for (int nt = 0; nt < 6; nt++)
                wn[nt] = ld_frag(wp + (s + 1) * 6144 + nt * 512);
        } else {
#pragma unroll
            for (int nt = 0; nt < 6; nt++) wn[nt] = wc[nt];
        }
        float4 e2a, e2b;
        if (s < 6) {
            e2a = *reinterpret_cast<const float4*>(ap + (s + 2) * 32);
            e2b = *reinterpret_cast<const float4*>(ap + (s + 2) * 32 + 4);
        } else { e2a = e1a; e2b = e1b; }

        u16x8 at;
        at[0] = f2bfbits(e0a.x); at[1] = f2bfbits(e0a.y);
        at[2] = f2bfbits(e0a.z); at[3] = f2bfbits(e0a.w);
        at[4] = f2bfbits(e0b.x); at[5] = f2bfbits(e0b.y);
        at[6] = f2bfbits(e0b.z); at[7] = f2bfbits(e0b.w);
        bf16x8 af = __builtin_bit_cast(bf16x8, at);

#pragma unroll
        for (int nt = 0; nt < 6; nt++)
            acc[nt] = __builtin_amdgcn_mfma_f32_16x16x32_bf16(af, wc[nt], acc[nt], 0, 0, 0);

        e0a = e1a; e0b = e1b; e1a = e2a; e1b = e2b;
#pragma unroll
        for (int nt = 0; nt < 6; nt++) wc[nt] = wn[nt];
    }

    // tree-merge the 4 k-partials within each n-half
    if (kq >= 2) {
        float* rp = &red[nh * 2 + (kq - 2)][lane * 25];
#pragma unroll
        for (int i = 0; i < 6; i++) *reinterpret_cast<f32x4*>(rp + i * 4) = acc[i];
    }
    __syncthreads();
    if (kq < 2) {
        float* rp = &red[nh * 2 + kq][lane * 25];
#pragma unroll
        for (int i = 0; i < 6; i++) acc[i] += *reinterpret_cast<const f32x4*>(rp + i * 4);
    }
    __syncthreads();
    if (kq == 1) {
        float* rp = &red[nh * 2][lane * 25];
#pragma unroll
        for (int i = 0; i < 6; i++) *reinterpret_cast<f32x4*>(rp + i * 4) = acc[i];
    }
    __syncthreads();
    if (kq == 0) {
        float* rp = &red[nh * 2][lane * 25];
#pragma unroll
        for (int i = 0; i < 6; i++) acc[i] += *reinterpret_cast<const f32x4*>(rp + i * 4);

#pragma unroll
        for (int nt = 0; nt < 6; nt++) {
            int n = nh * 96 + nt * 16 + c;
            float bias = (n < 64) ? bq[n] : (n < 128) ? bk[n - 64] : bv[n - 128];
            float fac = (n < 64) ? QSCALE : 1.0f;
#pragma unroll
            for (int r = 0; r < 4; r++) {
                int token = tb * 16 + qd * 4 + r;
                unsigned short bits = f2bfbits((acc[nt][r] + bias) * fac);
                if (n < 64)        Qb[(size_t)token * 64 + n] = bits;
                else if (n < 128)  Kb[(size_t)token * 64 + (n - 64)] = bits;
                else {
                    int bb = token >> 12, ss = token & 4095;
                    VT[((size_t)bb * 64 + (n - 128)) * SEQ + ss] = bits;
                }
            }
        }
    }
}

// ---------- kernel 3: flash attention (round-4 structure, 2 blocks/CU) ----------
// 512 thr = 8 waves; block = 64 q x tlen t; wave w owns slice tlen/8, steps of 64.
// K/V B-frags gathered from global (L2); P via per-wave LDS (pad 68 = 2-way banks).
// End: LDS tree-reduce over waves; partial out (t-split 2) or direct.
__global__ __launch_bounds__(512) void attn(
        const unsigned short* __restrict__ Qb, const unsigned short* __restrict__ Kb,
        const unsigned short* __restrict__ VT,
        float* __restrict__ accP, float* __restrict__ lP,
        float* __restrict__ outDirect, int tlen) {
    __shared__ __align__(16) unsigned short Pl[8][64 * 68];  // 69632 B, aliased as reduce buf
    __shared__ float l_all[8][64];

    const int tid = threadIdx.x;
    const int w = tid >> 6, lane = tid & 63;
    const int c = lane & 15, qd = lane >> 4;
    const int g3 = blockIdx.x & 7;               // XCD pin
    const int b = g3 >> 1;
    int tsp, qblk;
    if (outDirect) { tsp = 0; qblk = ((blockIdx.x >> 3) << 1) | (g3 & 1); }
    else           { tsp = g3 & 1; qblk = blockIdx.x >> 3; }
    const int qbase = qblk * 64;
    const int slice = tlen >> 3;
    const int tstart = tsp * tlen + w * slice;
    const int iters = slice >> 6;

    // Q A-fragments (shared by all 8 waves -> L1), pre-scaled by QSCALE
    bf16x8 aq0[4], aq1[4];
#pragma unroll
    for (int qs = 0; qs < 4; qs++) {
        const unsigned short* Qp = Qb + ((size_t)(b << 12) + qbase + qs * 16 + c) * 64 + qd * 8;
        aq0[qs] = ld_frag(Qp);
        aq1[qs] = ld_frag(Qp + 32);
    }

    f32x4 acc[16];                               // [qs][nt]
#pragma unroll
    for (int i = 0; i < 16; i++) acc[i] = (f32x4){0.f, 0.f, 0.f, 0.f};
    float lsum[4][4];
#pragma unroll
    for (int qs = 0; qs < 4; qs++)
#pragma unroll
        for (int r = 0; r < 4; r++) lsum[qs][r] = 0.f;

    unsigned short* myP = &Pl[w][0];

#pragma unroll 2
    for (int it = 0; it < iters; it++) {
        const int t0 = tstart + it * 64;
        const unsigned short* Kt = Kb + ((size_t)(b << 12) + t0) * 64;

        bf16x8 bk0[4], bk1[4];                   // K B-frags from global
#pragma unroll
        for (int ts = 0; ts < 4; ts++) {
            bk0[ts] = ld_frag(Kt + (ts * 16 + c) * 64 + qd * 8);
            bk1[ts] = ld_frag(Kt + (ts * 16 + c) * 64 + 32 + qd * 8);
        }

#pragma unroll
        for (int qs = 0; qs < 4; qs++) {
            f32x4 sc[4];
#pragma unroll
            for (int ts = 0; ts < 4; ts++) {
                f32x4 z = (f32x4){0.f, 0.f, 0.f, 0.f};
                z = __builtin_amdgcn_mfma_f32_16x16x32_bf16(aq0[qs], bk0[ts], z, 0, 0, 0);
                z = __builtin_amdgcn_mfma_f32_16x16x32_bf16(aq1[qs], bk1[ts], z, 0, 0, 0);
                sc[ts] = z;
            }
#pragma unroll
            for (int ts = 0; ts < 4; ts++)
#pragma unroll
                for (int r = 0; r < 4; r++) {
                    float p = __builtin_amdgcn_exp2f(sc[ts][r]);
                    lsum[qs][r] += p;
                    myP[(qs * 16 + qd * 4 + r) * 68 + ts * 16 + c] = f2bfbits(p);
                }
        }

        bf16x8 bv0[4], bv1[4];                   // V B-frags from global
#pragma unroll
        for (int nt = 0; nt < 4; nt++) {
            const unsigned short* Vp = VT + (((size_t)b * 64 + nt * 16 + c) << 12) + t0 + qd * 8;
            bv0[nt] = ld_frag(Vp);
            bv1[nt] = ld_frag(Vp + 32);
        }

#pragma unroll
        for (int qs = 0; qs < 4; qs++) {
            bf16x8 ap0 = ld_frag(&myP[(qs * 16 + c) * 68 + qd * 8]);
            bf16x8 ap1 = ld_frag(&myP[(qs * 16 + c) * 68 + 32 + qd * 8]);
#pragma unroll
            for (int nt = 0; nt < 4; nt++) {
                acc[qs * 4 + nt] = __builtin_amdgcn_mfma_f32_16x16x32_bf16(ap0, bv0[nt], acc[qs * 4 + nt], 0, 0, 0);
                acc[qs * 4 + nt] = __builtin_amdgcn_mfma_f32_16x16x32_bf16(ap1, bv1[nt], acc[qs * 4 + nt], 0, 0, 0);
            }
        }
    }

    // l reduction across the 16 column lanes (stays within quad-group)
#pragma unroll
    for (int off = 1; off < 16; off <<= 1)
#pragma unroll
        for (int qs = 0; qs < 4; qs++)
#pragma unroll
            for (int r = 0; r < 4; r++) lsum[qs][r] += __shfl_xor(lsum[qs][r], off);
    if (c == 0) {
#pragma unroll
        for (int qs = 0; qs < 4; qs++)
#pragma unroll
            for (int r = 0; r < 4; r++)
                l_all[w][qs * 16 + qd * 4 + r] = lsum[qs][r];
    }

    // tree-reduce acc over 8 waves; buffer aliases Pl (slot 4160 floats, stride 65)
    float* red = (float*)&Pl[0][0];
    __syncthreads();
    if (w >= 4) {
        float* rp = red + (w - 4) * 4160 + lane * 65;
#pragma unroll
        for (int i = 0; i < 16; i++) *reinterpret_cast<f32x4*>(rp + i * 4) = acc[i];
    }
    __syncthreads();
    if (w < 4) {
        float* rp = red + w * 4160 + lane * 65;
#pragma unroll
        for (int i = 0; i < 16; i++) acc[i] += *reinterpret_cast<const f32x4*>(rp + i * 4);
    }
    __syncthreads();
    if (w == 2 || w == 3) {
        float* rp = red + (w - 2) * 4160 + lane * 65;
#pragma unroll
        for (int i = 0; i < 16; i++) *reinterpret_cast<f32x4*>(rp + i * 4) = acc[i];
    }
    __syncthreads();
    if (w < 2) {
        float* rp = red + w * 4160 + lane * 65;
#pragma unroll
        for (int i = 0; i < 16; i++) acc[i] += *reinterpret_cast<const f32x4*>(rp + i * 4);
    }
    __syncthreads();
    if (w == 1) {
        float* rp = red + lane * 65;
#pragma unroll
        for (int i = 0; i < 16; i++) *reinterpret_cast<f32x4*>(rp + i * 4) = acc[i];
    }
    __syncthreads();
    if (w == 0) {
        float* rp = red + lane * 65;
#pragma unroll
        for (int i = 0; i < 16; i++) acc[i] += *reinterpret_cast<const f32x4*>(rp + i * 4);

#pragma unroll
        for (int qs = 0; qs < 4; qs++)
#pragma unroll
            for (int r = 0; r < 4; r++) {
                int q = qs * 16 + qd * 4 + r;
                float l = 0.f;
#pragma unroll
                for (int ww = 0; ww < 8; ww++) l += l_all[ww][q];
                size_t brow = (size_t)(b << 12) + qbase + q;
                if (outDirect) {
                    float inv = 1.0f / l;
#pragma unroll
                    for (int nt = 0; nt < 4; nt++)
                        outDirect[brow * 64 + nt * 16 + c] = acc[qs * 4 + nt][r] * inv;
                } else {
#pragma unroll
                    for (int nt = 0; nt < 4; nt++)
                        accP[((size_t)tsp * QTOT + brow) * 64 + nt * 16 + c] = acc[qs * 4 + nt][r];
                    if (c == 0) lP[(size_t)tsp * QTOT + brow] = l;
                }
            }
    }
}

// ---------- kernel 4: merge the 2 t-split partials ----------
__global__ __launch_bounds__(256) void merge_attn(
        const float* __restrict__ accP, const float* __restrict__ lP,
        float* __restrict__ out) {
    int idx4 = (blockIdx.x * 256 + threadIdx.x) * 4;   // over QTOT*64
    int q = idx4 >> 6;
    float4 a0 = *reinterpret_cast<const float4*>(accP + idx4);
    float4 a1 = *reinterpret_cast<const float4*>(accP + (size_t)QTOT * 64 + idx4);
    float inv = 1.0f / (lP[q] + lP[QTOT + q]);
    float4 o = {(a0.x + a1.x) * inv, (a0.y + a1.y) * inv,
                (a0.z + a1.z) * inv, (a0.w + a1.w) * inv};
    *reinterpret_cast<float4*>(out + idx4) = o;
}

// ---------- launch ----------
extern "C" void kernel_launch(void* const* d_in, const int* in_sizes, int n_in,
                              void* d_out, int out_size, void* d_ws, size_t ws_size,
                              hipStream_t stream) {
    const float* emb = (const float*)d_in[0];
    const float* Wq  = (const float*)d_in[1];
    const float* bq  = (const float*)d_in[2];
    const float* Wk  = (const float*)d_in[3];
    const float* bk  = (const float*)d_in[4];
    const float* Wv  = (const float*)d_in[5];
    const float* bv  = (const float*)d_in[6];
    float* out = (float*)d_out;

    unsigned short* ws = (unsigned short*)d_ws;
    unsigned short* WtS = ws;                      // 192*1024 ushort
    unsigned short* Qb = ws + 192 * 1024;          // QTOT*64 bf16
    unsigned short* Kb = Qb + QTOT * 64;           // QTOT*64 bf16
    unsigned short* VT = Kb + QTOT * 64;           // [b][v][t] bf16
    char* region = (char*)(VT + QTOT * 64);        // byte offset 6,684,672
    size_t avail = (ws_size > 6684672) ? ws_size - 6684672 : 0;
    size_t need = (size_t)2 * QTOT * 64 * 4 + (size_t)2 * QTOT * 4;  // 8.5 MB

    prep_weights<<<768, 256, 0, stream>>>(Wq, Wk, Wv, WtS);
    proj<<<1024, 512, 0, stream>>>(emb, WtS, bq, bk, bv, Qb, Kb, VT);

    if (avail >= need) {
        float* accP = (float*)region;
        float* lP   = accP + (size_t)2 * QTOT * 64;
        attn<<<512, 512, 0, stream>>>(Qb, Kb, VT, accP, lP, nullptr, 2048);
        merge_attn<<<(QTOT * 64) / 1024, 256, 0, stream>>>(accP, lP, out);
    } else {
        attn<<<256, 512, 0, stream>>>(Qb, Kb, VT, nullptr, nullptr, out, 4096);
    }
}